// Round 3
// baseline (391.954 us; speedup 1.0000x reference)
//
#include <hip/hip_runtime.h>
#include <math.h>

// Problem constants
#define BG   64      // graphs
#define NN   2048    // nodes per graph
#define DD   256     // hidden dim
#define CQ   16      // 12 class queries + 4 group queries fused

// Workspace layout (in floats)
//  q16     : [16][256]            at 0
//  h       : [4][512]             at 4096
//  scores  : [64][16][2048]       at 6144      (raw scores, then softmax p in-place)
//  partial : [64][P][16][256]     at 2103296
static constexpr size_t WS_Q16 = 0;
static constexpr size_t WS_H   = 4096;
static constexpr size_t WS_S   = 6144;
static constexpr size_t WS_P   = 6144 + (size_t)BG * CQ * NN;   // 2103296

// ---------------------------------------------------------------------------
// A1: h[g][j] = relu(q[g] . w1[g][:,j] + b1[g][j]); copy group queries to
// Q16 rows 12..15.  grid 64 = 4 groups x 16 j-chunks of 32, block 256.
__global__ __launch_bounds__(256) void kA1(const float* __restrict__ gq,
                                           const float* __restrict__ w1,
                                           const float* __restrict__ b1,
                                           float* __restrict__ ws) {
    int blk = blockIdx.x;
    int g   = blk >> 4;
    int jb  = (blk & 15) * 32;
    int t   = threadIdx.x;
    __shared__ float qlds[256];
    qlds[t] = gq[g * 256 + t];
    if ((blk & 15) == 0) ws[WS_Q16 + (12 + g) * 256 + t] = gq[g * 256 + t];
    __syncthreads();
    int jl = t & 31, dp = t >> 5;              // 32 j x 8 d-parts
    float acc = 0.f;
    const float* wp = w1 + ((size_t)g * 256) * 512 + jb + jl;
    #pragma unroll 8
    for (int i = 0; i < 32; ++i) {
        int d = dp * 32 + i;
        acc += qlds[d] * wp[(size_t)d * 512];
    }
    __shared__ float red[8][33];
    red[dp][jl] = acc;
    __syncthreads();
    if (dp == 0) {
        float s = 0.f;
        #pragma unroll
        for (int p = 0; p < 8; ++p) s += red[p][jl];
        s += b1[g * 512 + jb + jl];
        ws[WS_H + g * 512 + jb + jl] = fmaxf(s, 0.f);
    }
}

// A2: flat[g][k] = h[g] . w2[g][:,k] + b2[g][k] -> Q16 rows 0..11.
// grid 192 = 4 groups x 48 k-chunks of 16, block 256 (16 k x 16 d-parts).
__global__ __launch_bounds__(256) void kA2(const float* __restrict__ w2,
                                           const float* __restrict__ b2,
                                           float* __restrict__ ws) {
    int blk = blockIdx.x;
    int g   = blk / 48;
    int kb  = (blk % 48) * 16;
    int t   = threadIdx.x;
    __shared__ float hlds[512];
    hlds[t]       = ws[WS_H + g * 512 + t];
    hlds[t + 256] = ws[WS_H + g * 512 + t + 256];
    __syncthreads();
    int kl = t & 15, dp = t >> 4;              // 16 k x 16 d-parts (32 each)
    float acc = 0.f;
    const float* wp = w2 + ((size_t)g * 512) * 768 + kb + kl;
    #pragma unroll 8
    for (int i = 0; i < 32; ++i) {
        int jj = dp * 32 + i;
        acc += hlds[jj] * wp[(size_t)jj * 768];
    }
    __shared__ float red[16][17];
    red[dp][kl] = acc;
    __syncthreads();
    if (dp == 0) {
        float s = 0.f;
        #pragma unroll
        for (int p = 0; p < 16; ++p) s += red[p][kl];
        ws[WS_Q16 + g * 768 + kb + kl] = s + b2[g * 768 + kb + kl];
    }
}

// ---------------------------------------------------------------------------
// B: scores[b][c][n] = (Q16[c] . x[n]) / 16.  1 node/thread.
// Q is wave-uniform -> read through SGPRs (s_load), zero LDS.
// 8-deep explicit prefetch keeps >=8 x-loads in flight per thread.
// grid 512 blocks x 256 nodes, block 256.
__global__ __launch_bounds__(256) void kB(const float* __restrict__ x,
                                          const float* __restrict__ q16,
                                          float* __restrict__ scores) {
    int t  = threadIdx.x;
    int n0 = blockIdx.x * 256;
    const float4* xa = (const float4*)x + (size_t)(n0 + t) * 64;

    float acc[CQ];
    #pragma unroll
    for (int c = 0; c < CQ; ++c) acc[c] = 0.f;

    float4 buf[8];
    #pragma unroll
    for (int i = 0; i < 8; ++i) buf[i] = xa[i];

    #pragma unroll
    for (int base = 0; base < 64; base += 8) {
        float4 cur[8];
        #pragma unroll
        for (int i = 0; i < 8; ++i) cur[i] = buf[i];
        if (base + 8 < 64) {
            #pragma unroll
            for (int i = 0; i < 8; ++i) buf[i] = xa[base + 8 + i];
        }
        #pragma unroll
        for (int i = 0; i < 8; ++i) {
            #pragma unroll
            for (int c = 0; c < CQ; ++c) {
                const float* q = q16 + c * 256 + (base + i) * 4;  // uniform -> s_load
                acc[c] += q[0] * cur[i].x + q[1] * cur[i].y
                        + q[2] * cur[i].z + q[3] * cur[i].w;
            }
        }
    }
    int bgi = n0 >> 11;                        // 256 | 2048 so no straddle
    int nl  = n0 & 2047;
    float* srow = scores + (size_t)bgi * CQ * NN + nl;
    #pragma unroll
    for (int c = 0; c < CQ; ++c) srow[(size_t)c * NN + t] = acc[c] * 0.0625f;
}

// ---------------------------------------------------------------------------
// C: softmax over n per (b,c); normalized p in-place; rows c<12 also to
// attn12 output.  grid 1024 = b*16+c, block 256.
__global__ __launch_bounds__(256) void kC(float* __restrict__ scores,
                                          float* __restrict__ out_attn) {
    int bc = blockIdx.x;
    int b  = bc >> 4, c = bc & 15;
    int t  = threadIdx.x;
    int wave = t >> 6, lane = t & 63;
    float4* row = (float4*)(scores + (size_t)(b * CQ + c) * NN);
    float4 v1 = row[t];
    float4 v2 = row[t + 256];

    float m = fmaxf(fmaxf(fmaxf(v1.x, v1.y), fmaxf(v1.z, v1.w)),
                    fmaxf(fmaxf(v2.x, v2.y), fmaxf(v2.z, v2.w)));
    #pragma unroll
    for (int off = 32; off; off >>= 1) m = fmaxf(m, __shfl_xor(m, off, 64));
    __shared__ float wmax[4], wsum[4];
    if (lane == 0) wmax[wave] = m;
    __syncthreads();
    m = fmaxf(fmaxf(wmax[0], wmax[1]), fmaxf(wmax[2], wmax[3]));

    float4 e1, e2;
    e1.x = __expf(v1.x - m); e1.y = __expf(v1.y - m);
    e1.z = __expf(v1.z - m); e1.w = __expf(v1.w - m);
    e2.x = __expf(v2.x - m); e2.y = __expf(v2.y - m);
    e2.z = __expf(v2.z - m); e2.w = __expf(v2.w - m);
    float s = e1.x + e1.y + e1.z + e1.w + e2.x + e2.y + e2.z + e2.w;
    #pragma unroll
    for (int off = 32; off; off >>= 1) s += __shfl_xor(s, off, 64);
    if (lane == 0) wsum[wave] = s;
    __syncthreads();
    float inv = 1.f / (wsum[0] + wsum[1] + wsum[2] + wsum[3]);
    e1.x *= inv; e1.y *= inv; e1.z *= inv; e1.w *= inv;
    e2.x *= inv; e2.y *= inv; e2.z *= inv; e2.w *= inv;
    row[t]       = e1;
    row[t + 256] = e2;
    if (c < 12) {
        float4* ar = (float4*)out_attn + (size_t)(b * 12 + c) * (NN / 4);
        ar[t]       = e1;
        ar[t + 256] = e2;
    }
}

// ---------------------------------------------------------------------------
// D: partial pooled.  grid 64*P = (b,part); block 256 (4 waves x 64 lanes).
// Wave handles NN/P/4 consecutive nodes; lane owns one float4 of D.
// p is wave-uniform (readfirstlane'd wave id) -> s_load through K$.
template<int P>
__global__ __launch_bounds__(256) void kD(const float* __restrict__ x,
                                          const float* __restrict__ p,
                                          float* __restrict__ partial) {
    constexpr int NPB = NN / P;                 // nodes per block
    constexpr int NPW = NPB / 4;                // nodes per wave
    int blk = blockIdx.x;
    int b = blk / P, part = blk % P;
    int t = threadIdx.x;
    int wave = __builtin_amdgcn_readfirstlane(t >> 6);  // provably uniform
    int lane = t & 63;

    float4 acc[CQ];
    #pragma unroll
    for (int c = 0; c < CQ; ++c) acc[c] = make_float4(0.f, 0.f, 0.f, 0.f);

    const float4* xf = (const float4*)x;
    int nbase = part * NPB + wave * NPW;        // graph-local, uniform
    size_t xrow = ((size_t)b * NN + nbase) * 64 + lane;
    const float* pr = p + (size_t)b * CQ * NN + nbase;  // uniform base

    #pragma unroll
    for (int nn = 0; nn < NPW; nn += 8) {
        float4 xv[8];
        #pragma unroll
        for (int i = 0; i < 8; ++i) xv[i] = xf[xrow + (size_t)(nn + i) * 64];
        #pragma unroll
        for (int i = 0; i < 8; ++i) {
            #pragma unroll
            for (int c = 0; c < CQ; ++c) {
                float pv = pr[c * NN + nn + i];          // uniform -> s_load
                acc[c].x += pv * xv[i].x;
                acc[c].y += pv * xv[i].y;
                acc[c].z += pv * xv[i].z;
                acc[c].w += pv * xv[i].w;
            }
        }
    }

    __shared__ float sdata[CQ * 256];
    for (int w = 0; w < 4; ++w) {
        if ((t >> 6) == w) {
            #pragma unroll
            for (int c = 0; c < CQ; ++c) {
                float* dst = &sdata[c * 256 + lane * 4];
                if (w == 0) {
                    dst[0] = acc[c].x; dst[1] = acc[c].y;
                    dst[2] = acc[c].z; dst[3] = acc[c].w;
                } else {
                    dst[0] += acc[c].x; dst[1] += acc[c].y;
                    dst[2] += acc[c].z; dst[3] += acc[c].w;
                }
            }
        }
        __syncthreads();
    }
    float* po = partial + (size_t)blk * (CQ * 256);
    for (int i = t; i < CQ * 256; i += 256) po[i] = sdata[i];
}

// ---------------------------------------------------------------------------
// E: reduce P partials -> pooled row; LayerNorm; Linear(256,128)+ReLU;
// Linear(128,1) -> logits.  grid 1024 = b*16+c, block 256.
template<int P>
__global__ __launch_bounds__(256) void kE(const float* __restrict__ partial,
        const float* __restrict__ lnG12, const float* __restrict__ lnB12,
        const float* __restrict__ wA12,  const float* __restrict__ bA12,
        const float* __restrict__ wB12,  const float* __restrict__ bB12,
        const float* __restrict__ lnG4,  const float* __restrict__ lnB4,
        const float* __restrict__ wA4,   const float* __restrict__ bA4,
        const float* __restrict__ wB4,   const float* __restrict__ bB4,
        float* __restrict__ out) {
    int bc = blockIdx.x;
    int b = bc >> 4, c = bc & 15;
    int t = threadIdx.x, wave = t >> 6, lane = t & 63;

    float v = 0.f;
    size_t base = ((size_t)b * P * CQ + c) * 256 + t;
    #pragma unroll
    for (int part = 0; part < P; ++part) v += partial[base + (size_t)part * (CQ * 256)];

    __shared__ float wr1[4], wr2[4];
    float s = v;
    #pragma unroll
    for (int off = 32; off; off >>= 1) s += __shfl_xor(s, off, 64);
    if (lane == 0) wr1[wave] = s;
    __syncthreads();
    float mu = (wr1[0] + wr1[1] + wr1[2] + wr1[3]) * (1.f / 256.f);
    float dv = v - mu;
    s = dv * dv;
    #pragma unroll
    for (int off = 32; off; off >>= 1) s += __shfl_xor(s, off, 64);
    if (lane == 0) wr2[wave] = s;
    __syncthreads();
    float var = (wr2[0] + wr2[1] + wr2[2] + wr2[3]) * (1.f / 256.f);

    bool is12 = (c < 12);
    const float* lg = is12 ? lnG12 : lnG4;
    const float* lb = is12 ? lnB12 : lnB4;
    const float* wA = is12 ? wA12  : wA4;
    const float* bA = is12 ? bA12  : bA4;
    const float* wB = is12 ? wB12  : wB4;
    const float* bB = is12 ? bB12  : bB4;

    __shared__ float ylds[256];
    __shared__ float hred[256];
    __shared__ float hlds[128];
    float y = dv * rsqrtf(var + 1e-5f) * lg[t] + lb[t];
    ylds[t] = y;
    __syncthreads();
    {
        int j = t & 127, half = t >> 7;
        float hh = 0.f;
        const float* wc = wA + (size_t)half * 128 * 128 + j;
        #pragma unroll 4
        for (int d = 0; d < 128; ++d) hh += ylds[half * 128 + d] * wc[(size_t)d * 128];
        hred[t] = hh;
    }
    __syncthreads();
    if (t < 128) hlds[t] = fmaxf(hred[t] + hred[t + 128] + bA[t], 0.f);
    __syncthreads();
    if (t < 64) {
        float pp = hlds[t] * wB[t] + hlds[t + 64] * wB[t + 64];
        #pragma unroll
        for (int off = 32; off; off >>= 1) pp += __shfl_xor(pp, off, 64);
        if (t == 0) {
            float logit = pp + bB[0];
            if (is12) out[b * 12 + c] = logit;
            else      out[768 + b * 4 + (c - 12)] = logit;
        }
    }
}

// ---------------------------------------------------------------------------
extern "C" void kernel_launch(void* const* d_in, const int* in_sizes, int n_in,
                              void* d_out, int out_size, void* d_ws, size_t ws_size,
                              hipStream_t stream) {
    const float* x     = (const float*)d_in[0];   // [131072, 256]
    const float* gq    = (const float*)d_in[2];   // [4, 256]
    const float* w1    = (const float*)d_in[3];   // [4, 256, 512]
    const float* b1    = (const float*)d_in[4];   // [4, 512]
    const float* w2    = (const float*)d_in[5];   // [4, 512, 768]
    const float* b2    = (const float*)d_in[6];   // [4, 768]
    const float* ln12g = (const float*)d_in[7];
    const float* ln12b = (const float*)d_in[8];
    const float* w12a  = (const float*)d_in[9];   // [256, 128]
    const float* b12a  = (const float*)d_in[10];
    const float* w12b  = (const float*)d_in[11];  // [128, 1]
    const float* b12b  = (const float*)d_in[12];
    const float* ln4g  = (const float*)d_in[13];
    const float* ln4b  = (const float*)d_in[14];
    const float* w4a   = (const float*)d_in[15];
    const float* b4a   = (const float*)d_in[16];
    const float* w4b   = (const float*)d_in[17];
    const float* b4b   = (const float*)d_in[18];

    float* out     = (float*)d_out;               // [768 logits12][256 logits4][1572864 attn12]
    float* ws      = (float*)d_ws;
    float* q16     = ws + WS_Q16;
    float* scores  = ws + WS_S;
    float* partial = ws + WS_P;

    kA1<<<64,  256, 0, stream>>>(gq, w1, b1, ws);
    kA2<<<192, 256, 0, stream>>>(w2, b2, ws);
    kB <<<512, 256, 0, stream>>>(x, q16, scores);
    kC <<<1024,256, 0, stream>>>(scores, out + 1024);

    size_t need16 = (WS_P + (size_t)BG * 16 * CQ * 256) * sizeof(float);
    size_t need8  = (WS_P + (size_t)BG * 8  * CQ * 256) * sizeof(float);
    if (ws_size >= need16) {
        kD<16><<<BG * 16, 256, 0, stream>>>(x, scores, partial);
        kE<16><<<1024, 256, 0, stream>>>(partial,
                ln12g, ln12b, w12a, b12a, w12b, b12b,
                ln4g,  ln4b,  w4a,  b4a,  w4b,  b4b, out);
    } else if (ws_size >= need8) {
        kD<8><<<BG * 8, 256, 0, stream>>>(x, scores, partial);
        kE<8><<<1024, 256, 0, stream>>>(partial,
                ln12g, ln12b, w12a, b12a, w12b, b12b,
                ln4g,  ln4b,  w4a,  b4a,  w4b,  b4b, out);
    } else {
        kD<4><<<BG * 4, 256, 0, stream>>>(x, scores, partial);
        kE<4><<<1024, 256, 0, stream>>>(partial,
                ln12g, ln12b, w12a, b12a, w12b, b12b,
                ln4g,  ln4b,  w4a,  b4a,  w4b,  b4b, out);
    }
}

// Round 6
// 305.712 us; speedup vs baseline: 1.2821x; 1.2821x over previous
//
#include <hip/hip_runtime.h>
#include <math.h>

// Problem constants
#define BG   64      // graphs
#define NN   2048    // nodes per graph
#define DD   256     // hidden dim
#define CQ   16      // 12 class queries + 4 group queries fused
#define PP   16      // node partitions per graph for kD (ws is ~512MB, fits)

// Workspace layout (in floats)
//  q16     : [16][256]            at 0
//  h       : [4][512]             at 4096
//  scores  : [64][16][2048]       at 6144      (raw scores, then softmax p in-place)
//  partial : [64][PP][16][256]    at 2103296
static constexpr size_t WS_Q16 = 0;
static constexpr size_t WS_H   = 4096;
static constexpr size_t WS_S   = 6144;
static constexpr size_t WS_P   = 6144 + (size_t)BG * CQ * NN;   // 2103296

// ---------------------------------------------------------------------------
// A1: h[g][j] = relu(q[g] . w1[g][:,j] + b1[g][j]); copy group queries to
// Q16 rows 12..15.  grid 64 = 4 groups x 16 j-chunks of 32, block 256.
__global__ __launch_bounds__(256) void kA1(const float* __restrict__ gq,
                                           const float* __restrict__ w1,
                                           const float* __restrict__ b1,
                                           float* __restrict__ ws) {
    int blk = blockIdx.x;
    int g   = blk >> 4;
    int jb  = (blk & 15) * 32;
    int t   = threadIdx.x;
    __shared__ float qlds[256];
    qlds[t] = gq[g * 256 + t];
    if ((blk & 15) == 0) ws[WS_Q16 + (12 + g) * 256 + t] = gq[g * 256 + t];
    __syncthreads();
    int jl = t & 31, dp = t >> 5;              // 32 j x 8 d-parts
    float acc = 0.f;
    const float* wp = w1 + ((size_t)g * 256) * 512 + jb + jl;
    for (int i = 0; i < 32; ++i) {
        int d = dp * 32 + i;
        acc += qlds[d] * wp[(size_t)d * 512];
    }
    __shared__ float red[8][33];
    red[dp][jl] = acc;
    __syncthreads();
    if (dp == 0) {
        float s = 0.f;
        for (int p = 0; p < 8; ++p) s += red[p][jl];
        s += b1[g * 512 + jb + jl];
        ws[WS_H + g * 512 + jb + jl] = fmaxf(s, 0.f);
    }
}

// A2: flat[g][k] = h[g] . w2[g][:,k] + b2[g][k] -> Q16 rows 0..11.
// grid 192 = 4 groups x 48 k-chunks of 16, block 256 (16 k x 16 d-parts).
__global__ __launch_bounds__(256) void kA2(const float* __restrict__ w2,
                                           const float* __restrict__ b2,
                                           float* __restrict__ ws) {
    int blk = blockIdx.x;
    int g   = blk / 48;
    int kb  = (blk % 48) * 16;
    int t   = threadIdx.x;
    __shared__ float hlds[512];
    hlds[t]       = ws[WS_H + g * 512 + t];
    hlds[t + 256] = ws[WS_H + g * 512 + t + 256];
    __syncthreads();
    int kl = t & 15, dp = t >> 4;              // 16 k x 16 d-parts (32 each)
    float acc = 0.f;
    const float* wp = w2 + ((size_t)g * 512) * 768 + kb + kl;
    for (int i = 0; i < 32; ++i) {
        int jj = dp * 32 + i;
        acc += hlds[jj] * wp[(size_t)jj * 768];
    }
    __shared__ float red[16][17];
    red[dp][kl] = acc;
    __syncthreads();
    if (dp == 0) {
        float s = 0.f;
        for (int p = 0; p < 16; ++p) s += red[p][kl];
        ws[WS_Q16 + g * 768 + kb + kl] = s + b2[g * 768 + kb + kl];
    }
}

// ---------------------------------------------------------------------------
// B: scores[b][c][n] = (Q16[c] . x[n]) / 16.  1 node/thread.
// Q staged in LDS (broadcast ds_read, conflict-free).  8-deep explicit x
// prefetch keeps 8 independent 16B loads in flight per thread.
// grid 512 blocks x 256 nodes, block 256.
__global__ __launch_bounds__(256) void kB(const float* __restrict__ x,
                                          const float* __restrict__ q16,
                                          float* __restrict__ scores) {
    __shared__ float4 qlds[CQ * 64];           // [c][d-chunk]
    int t = threadIdx.x;
    const float4* qg = (const float4*)q16;
    for (int i = 0; i < 4; ++i) qlds[t + i * 256] = qg[t + i * 256];
    __syncthreads();

    int n0 = blockIdx.x * 256;
    const float4* xa = (const float4*)x + (size_t)(n0 + t) * 64;

    float acc[CQ];
    #pragma unroll
    for (int c = 0; c < CQ; ++c) acc[c] = 0.f;

    float4 buf[8];
    #pragma unroll
    for (int i = 0; i < 8; ++i) buf[i] = xa[i];

    for (int base = 0; base < 64; base += 8) {
        float4 cur[8];
        #pragma unroll
        for (int i = 0; i < 8; ++i) cur[i] = buf[i];
        if (base + 8 < 64) {
            #pragma unroll
            for (int i = 0; i < 8; ++i) buf[i] = xa[base + 8 + i];
        }
        #pragma unroll
        for (int i = 0; i < 8; ++i) {
            #pragma unroll
            for (int c = 0; c < CQ; ++c) {
                float4 q = qlds[c * 64 + base + i];
                acc[c] += q.x * cur[i].x + q.y * cur[i].y
                        + q.z * cur[i].z + q.w * cur[i].w;
            }
        }
    }
    int bgi = n0 >> 11;                        // 256 | 2048 so no straddle
    int nl  = n0 & 2047;
    float* srow = scores + (size_t)bgi * CQ * NN + nl;
    #pragma unroll
    for (int c = 0; c < CQ; ++c) srow[(size_t)c * NN + t] = acc[c] * 0.0625f;
}

// ---------------------------------------------------------------------------
// C: softmax over n per (b,c); normalized p in-place; rows c<12 also to
// attn12 output.  grid 1024 = b*16+c, block 256.
__global__ __launch_bounds__(256) void kC(float* __restrict__ scores,
                                          float* __restrict__ out_attn) {
    int bc = blockIdx.x;
    int b  = bc >> 4, c = bc & 15;
    int t  = threadIdx.x;
    int wave = t >> 6, lane = t & 63;
    float4* row = (float4*)(scores + (size_t)(b * CQ + c) * NN);
    float4 v1 = row[t];
    float4 v2 = row[t + 256];

    float m = fmaxf(fmaxf(fmaxf(v1.x, v1.y), fmaxf(v1.z, v1.w)),
                    fmaxf(fmaxf(v2.x, v2.y), fmaxf(v2.z, v2.w)));
    #pragma unroll
    for (int off = 32; off; off >>= 1) m = fmaxf(m, __shfl_xor(m, off, 64));
    __shared__ float wmax[4], wsum[4];
    if (lane == 0) wmax[wave] = m;
    __syncthreads();
    m = fmaxf(fmaxf(wmax[0], wmax[1]), fmaxf(wmax[2], wmax[3]));

    float4 e1, e2;
    e1.x = __expf(v1.x - m); e1.y = __expf(v1.y - m);
    e1.z = __expf(v1.z - m); e1.w = __expf(v1.w - m);
    e2.x = __expf(v2.x - m); e2.y = __expf(v2.y - m);
    e2.z = __expf(v2.z - m); e2.w = __expf(v2.w - m);
    float s = e1.x + e1.y + e1.z + e1.w + e2.x + e2.y + e2.z + e2.w;
    #pragma unroll
    for (int off = 32; off; off >>= 1) s += __shfl_xor(s, off, 64);
    if (lane == 0) wsum[wave] = s;
    __syncthreads();
    float inv = 1.f / (wsum[0] + wsum[1] + wsum[2] + wsum[3]);
    e1.x *= inv; e1.y *= inv; e1.z *= inv; e1.w *= inv;
    e2.x *= inv; e2.y *= inv; e2.z *= inv; e2.w *= inv;
    row[t]       = e1;
    row[t + 256] = e2;
    if (c < 12) {
        float4* ar = (float4*)out_attn + (size_t)(b * 12 + c) * (NN / 4);
        ar[t]       = e1;
        ar[t + 256] = e2;
    }
}

// ---------------------------------------------------------------------------
// D: partial pooled.  grid 64*PP = (b,part); block 256 (4 waves x 64 lanes).
// Wave handles NN/PP/4 = 32 consecutive nodes; lane owns one float4 of D ->
// x loads are 1KB fully-coalesced per wave; p loads are broadcast float4.
__global__ __launch_bounds__(256) void kD(const float* __restrict__ x,
                                          const float* __restrict__ p,
                                          float* __restrict__ partial) {
    constexpr int NPB = NN / PP;                // 128 nodes per block
    constexpr int NPW = NPB / 4;                // 32 nodes per wave
    int blk = blockIdx.x;
    int b = blk / PP, part = blk % PP;
    int t = threadIdx.x, wave = t >> 6, lane = t & 63;

    float4 acc[CQ];
    #pragma unroll
    for (int c = 0; c < CQ; ++c) acc[c] = make_float4(0.f, 0.f, 0.f, 0.f);

    const float4* xf = (const float4*)x;
    const float4* pf = (const float4*)p;
    int nbase = part * NPB + wave * NPW;        // graph-local
    size_t xrow = ((size_t)b * NN + nbase) * 64 + lane;
    size_t prow = (size_t)b * CQ * (NN / 4) + (nbase >> 2);

    for (int nn = 0; nn < NPW; nn += 4) {
        float4 x0 = xf[xrow + (size_t)nn * 64];
        float4 x1 = xf[xrow + (size_t)(nn + 1) * 64];
        float4 x2 = xf[xrow + (size_t)(nn + 2) * 64];
        float4 x3 = xf[xrow + (size_t)(nn + 3) * 64];
        #pragma unroll
        for (int c = 0; c < CQ; ++c) {
            float4 pv = pf[prow + (size_t)c * (NN / 4) + (nn >> 2)];
            acc[c].x += pv.x * x0.x + pv.y * x1.x + pv.z * x2.x + pv.w * x3.x;
            acc[c].y += pv.x * x0.y + pv.y * x1.y + pv.z * x2.y + pv.w * x3.y;
            acc[c].z += pv.x * x0.z + pv.y * x1.z + pv.z * x2.z + pv.w * x3.z;
            acc[c].w += pv.x * x0.w + pv.y * x1.w + pv.z * x2.w + pv.w * x3.w;
        }
    }

    __shared__ float sdata[CQ * 256];
    for (int w = 0; w < 4; ++w) {
        if (wave == w) {
            #pragma unroll
            for (int c = 0; c < CQ; ++c) {
                float* dst = &sdata[c * 256 + lane * 4];
                if (w == 0) {
                    dst[0] = acc[c].x; dst[1] = acc[c].y;
                    dst[2] = acc[c].z; dst[3] = acc[c].w;
                } else {
                    dst[0] += acc[c].x; dst[1] += acc[c].y;
                    dst[2] += acc[c].z; dst[3] += acc[c].w;
                }
            }
        }
        __syncthreads();
    }
    float* po = partial + (size_t)blk * (CQ * 256);
    for (int i = t; i < CQ * 256; i += 256) po[i] = sdata[i];
}

// ---------------------------------------------------------------------------
// E: reduce PP partials -> pooled row; LayerNorm; Linear(256,128)+ReLU;
// Linear(128,1) -> logits.  grid 1024 = b*16+c, block 256.
__global__ __launch_bounds__(256) void kE(const float* __restrict__ partial,
        const float* __restrict__ lnG12, const float* __restrict__ lnB12,
        const float* __restrict__ wA12,  const float* __restrict__ bA12,
        const float* __restrict__ wB12,  const float* __restrict__ bB12,
        const float* __restrict__ lnG4,  const float* __restrict__ lnB4,
        const float* __restrict__ wA4,   const float* __restrict__ bA4,
        const float* __restrict__ wB4,   const float* __restrict__ bB4,
        float* __restrict__ out) {
    int bc = blockIdx.x;
    int b = bc >> 4, c = bc & 15;
    int t = threadIdx.x, wave = t >> 6, lane = t & 63;

    float v = 0.f;
    size_t base = ((size_t)b * PP * CQ + c) * 256 + t;
    for (int part = 0; part < PP; ++part) v += partial[base + (size_t)part * (CQ * 256)];

    __shared__ float wr1[4], wr2[4];
    float s = v;
    #pragma unroll
    for (int off = 32; off; off >>= 1) s += __shfl_xor(s, off, 64);
    if (lane == 0) wr1[wave] = s;
    __syncthreads();
    float mu = (wr1[0] + wr1[1] + wr1[2] + wr1[3]) * (1.f / 256.f);
    float dv = v - mu;
    s = dv * dv;
    #pragma unroll
    for (int off = 32; off; off >>= 1) s += __shfl_xor(s, off, 64);
    if (lane == 0) wr2[wave] = s;
    __syncthreads();
    float var = (wr2[0] + wr2[1] + wr2[2] + wr2[3]) * (1.f / 256.f);

    bool is12 = (c < 12);
    const float* lg = is12 ? lnG12 : lnG4;
    const float* lb = is12 ? lnB12 : lnB4;
    const float* wA = is12 ? wA12  : wA4;
    const float* bA = is12 ? bA12  : bA4;
    const float* wB = is12 ? wB12  : wB4;
    const float* bB = is12 ? bB12  : bB4;

    __shared__ float ylds[256];
    __shared__ float hred[256];
    __shared__ float hlds[128];
    float y = dv * rsqrtf(var + 1e-5f) * lg[t] + lb[t];
    ylds[t] = y;
    __syncthreads();
    {
        int j = t & 127, half = t >> 7;
        float hh = 0.f;
        const float* wc = wA + (size_t)half * 128 * 128 + j;
        for (int d = 0; d < 128; ++d) hh += ylds[half * 128 + d] * wc[(size_t)d * 128];
        hred[t] = hh;
    }
    __syncthreads();
    if (t < 128) hlds[t] = fmaxf(hred[t] + hred[t + 128] + bA[t], 0.f);
    __syncthreads();
    if (t < 64) {
        float pp = hlds[t] * wB[t] + hlds[t + 64] * wB[t + 64];
        #pragma unroll
        for (int off = 32; off; off >>= 1) pp += __shfl_xor(pp, off, 64);
        if (t == 0) {
            float logit = pp + bB[0];
            if (is12) out[b * 12 + c] = logit;
            else      out[768 + b * 4 + (c - 12)] = logit;
        }
    }
}

// ---------------------------------------------------------------------------
extern "C" void kernel_launch(void* const* d_in, const int* in_sizes, int n_in,
                              void* d_out, int out_size, void* d_ws, size_t ws_size,
                              hipStream_t stream) {
    const float* x     = (const float*)d_in[0];   // [131072, 256]
    const float* gq    = (const float*)d_in[2];   // [4, 256]
    const float* w1    = (const float*)d_in[3];   // [4, 256, 512]
    const float* b1    = (const float*)d_in[4];   // [4, 512]
    const float* w2    = (const float*)d_in[5];   // [4, 512, 768]
    const float* b2    = (const float*)d_in[6];   // [4, 768]
    const float* ln12g = (const float*)d_in[7];
    const float* ln12b = (const float*)d_in[8];
    const float* w12a  = (const float*)d_in[9];   // [256, 128]
    const float* b12a  = (const float*)d_in[10];
    const float* w12b  = (const float*)d_in[11];  // [128, 1]
    const float* b12b  = (const float*)d_in[12];
    const float* ln4g  = (const float*)d_in[13];
    const float* ln4b  = (const float*)d_in[14];
    const float* w4a   = (const float*)d_in[15];
    const float* b4a   = (const float*)d_in[16];
    const float* w4b   = (const float*)d_in[17];
    const float* b4b   = (const float*)d_in[18];

    float* out     = (float*)d_out;               // [768 logits12][256 logits4][1572864 attn12]
    float* ws      = (float*)d_ws;
    float* q16     = ws + WS_Q16;
    float* scores  = ws + WS_S;
    float* partial = ws + WS_P;

    kA1<<<64,  256, 0, stream>>>(gq, w1, b1, ws);
    kA2<<<192, 256, 0, stream>>>(w2, b2, ws);
    kB <<<512, 256, 0, stream>>>(x, q16, scores);
    kC <<<1024,256, 0, stream>>>(scores, out + 1024);
    kD <<<BG * PP, 256, 0, stream>>>(x, scores, partial);
    kE <<<1024, 256, 0, stream>>>(partial,
            ln12g, ln12b, w12a, b12a, w12b, b12b,
            ln4g,  ln4b,  w4a,  b4a,  w4b,  b4b, out);
}

// Round 7
// 289.787 us; speedup vs baseline: 1.3526x; 1.0550x over previous
//
#include <hip/hip_runtime.h>
#include <math.h>

// Problem constants
#define BG   64      // graphs
#define NN   2048    // nodes per graph
#define DD   256     // hidden dim
#define CQ   16      // 12 class queries + 4 group queries fused
#define NCH  8       // 256-node chunks per graph

// Workspace layout (in floats)
static constexpr size_t WS_Q16 = 0;                                  // [16][256]
static constexpr size_t WS_H   = 4096;                               // [4][512]
static constexpr size_t WS_S   = 6144;                               // scores [64][16][2048]
static constexpr size_t WS_ML  = WS_S + (size_t)BG * CQ * NN;        // [64*8][32] chunk m|l
static constexpr size_t WS_PL  = WS_ML + (size_t)BG * NCH * 32;      // pooled [64*8][16][256]
static constexpr size_t WS_FML = WS_PL + (size_t)BG * NCH * CQ * DD; // final m [1024]
static constexpr size_t WS_FIL = WS_FML + 1024;                      // final 1/l [1024]

// ---------------------------------------------------------------------------
// A1: h[g][j] = relu(q[g] . w1[g][:,j] + b1[g][j]); copy group queries to
// Q16 rows 12..15.  grid 64 = 4 groups x 16 j-chunks of 32, block 256.
__global__ __launch_bounds__(256) void kA1(const float* __restrict__ gq,
                                           const float* __restrict__ w1,
                                           const float* __restrict__ b1,
                                           float* __restrict__ ws) {
    int blk = blockIdx.x;
    int g   = blk >> 4;
    int jb  = (blk & 15) * 32;
    int t   = threadIdx.x;
    __shared__ float qlds[256];
    qlds[t] = gq[g * 256 + t];
    if ((blk & 15) == 0) ws[WS_Q16 + (12 + g) * 256 + t] = gq[g * 256 + t];
    __syncthreads();
    int jl = t & 31, dp = t >> 5;              // 32 j x 8 d-parts
    float acc = 0.f;
    const float* wp = w1 + ((size_t)g * 256) * 512 + jb + jl;
    #pragma unroll 8
    for (int i = 0; i < 32; ++i) {
        int d = dp * 32 + i;
        acc += qlds[d] * wp[(size_t)d * 512];
    }
    __shared__ float red[8][33];
    red[dp][jl] = acc;
    __syncthreads();
    if (dp == 0) {
        float s = 0.f;
        #pragma unroll
        for (int p = 0; p < 8; ++p) s += red[p][jl];
        s += b1[g * 512 + jb + jl];
        ws[WS_H + g * 512 + jb + jl] = fmaxf(s, 0.f);
    }
}

// A2: flat[g][k] = h[g] . w2[g][:,k] + b2[g][k] -> Q16 rows 0..11.
// grid 192 = 4 groups x 48 k-chunks of 16, block 256 (16 k x 16 d-parts).
__global__ __launch_bounds__(256) void kA2(const float* __restrict__ w2,
                                           const float* __restrict__ b2,
                                           float* __restrict__ ws) {
    int blk = blockIdx.x;
    int g   = blk / 48;
    int kb  = (blk % 48) * 16;
    int t   = threadIdx.x;
    __shared__ float hlds[512];
    hlds[t]       = ws[WS_H + g * 512 + t];
    hlds[t + 256] = ws[WS_H + g * 512 + t + 256];
    __syncthreads();
    int kl = t & 15, dp = t >> 4;              // 16 k x 16 d-parts (32 each)
    float acc = 0.f;
    const float* wp = w2 + ((size_t)g * 512) * 768 + kb + kl;
    #pragma unroll 8
    for (int i = 0; i < 32; ++i) {
        int jj = dp * 32 + i;
        acc += hlds[jj] * wp[(size_t)jj * 768];
    }
    __shared__ float red[16][17];
    red[dp][kl] = acc;
    __syncthreads();
    if (dp == 0) {
        float s = 0.f;
        #pragma unroll
        for (int p = 0; p < 16; ++p) s += red[p][kl];
        ws[WS_Q16 + g * 768 + kb + kl] = s + b2[g * 768 + kb + kl];
    }
}

// ---------------------------------------------------------------------------
// F: fused scores + chunk-softmax-partials + chunk pooling.
// grid 512 = (b, chunk of 256 nodes); block 256 (4 waves).
// Phase 1: thread = node; stream x (8-deep prefetch); q16 via LDS broadcast;
//          write raw scaled scores to ws.
// Phase 2: per-c chunk max & sumexp (LDS + 16-lane shfl); exp-weights -> LDS.
// Phase 3: kD-style pooling: wave owns 64 nodes, lane owns float4 of D;
//          x re-read from global (chunk is L2/LLC-hot); weights broadcast
//          from LDS.  Emits (m,l) + pooled[16][256] per chunk.
__global__ __launch_bounds__(256) void kF(const float* __restrict__ x,
                                          float* __restrict__ ws) {
    __shared__ float4 qlds[CQ * 64];           // 16 KB: q16 [c][d4]; reused as combine scratch
    __shared__ float  wlds[CQ * 256];          // 16 KB: scores then exp-weights [c][n]
    __shared__ float  mbuf[CQ], lbuf[CQ];

    int t   = threadIdx.x;
    int blk = blockIdx.x;
    int b   = blk >> 3, ch = blk & 7;
    int gn0 = b * NN + ch * 256;               // global node base of this chunk

    const float4* qg = (const float4*)(ws + WS_Q16);
    #pragma unroll
    for (int i = 0; i < 4; ++i) qlds[t + i * 256] = qg[t + i * 256];
    __syncthreads();

    // ---- Phase 1: scores (thread = node gn0 + t) ----
    const float4* xa = (const float4*)x + (size_t)(gn0 + t) * 64;
    float sc[CQ];
    #pragma unroll
    for (int c = 0; c < CQ; ++c) sc[c] = 0.f;

    float4 buf[8];
    #pragma unroll
    for (int i = 0; i < 8; ++i) buf[i] = xa[i];
    for (int base = 0; base < 64; base += 8) {
        float4 cur[8];
        #pragma unroll
        for (int i = 0; i < 8; ++i) cur[i] = buf[i];
        if (base + 8 < 64) {
            #pragma unroll
            for (int i = 0; i < 8; ++i) buf[i] = xa[base + 8 + i];
        }
        #pragma unroll
        for (int i = 0; i < 8; ++i) {
            #pragma unroll
            for (int c = 0; c < CQ; ++c) {
                float4 q = qlds[c * 64 + base + i];
                sc[c] += q.x * cur[i].x + q.y * cur[i].y
                       + q.z * cur[i].z + q.w * cur[i].w;
            }
        }
    }
    #pragma unroll
    for (int c = 0; c < CQ; ++c) sc[c] *= 0.0625f;

    // raw scores to ws (needed by kAttn)
    float* srow = ws + WS_S + ((size_t)b * CQ) * NN + ch * 256;
    #pragma unroll
    for (int c = 0; c < CQ; ++c) srow[(size_t)c * NN + t] = sc[c];

    // ---- Phase 2: chunk max / sumexp per c ----
    #pragma unroll
    for (int c = 0; c < CQ; ++c) wlds[c * 256 + t] = sc[c];
    __syncthreads();
    {
        int c = t >> 4, slot = t & 15;
        float mv = -1e30f;
        #pragma unroll
        for (int k = 0; k < 16; ++k) mv = fmaxf(mv, wlds[c * 256 + slot + k * 16]);
        #pragma unroll
        for (int off = 1; off < 16; off <<= 1) mv = fmaxf(mv, __shfl_xor(mv, off, 64));
        if (slot == 0) mbuf[c] = mv;
    }
    __syncthreads();
    #pragma unroll
    for (int c = 0; c < CQ; ++c) wlds[c * 256 + t] = __expf(sc[c] - mbuf[c]);
    __syncthreads();
    {
        int c = t >> 4, slot = t & 15;
        float lv = 0.f;
        #pragma unroll
        for (int k = 0; k < 16; ++k) lv += wlds[c * 256 + slot + k * 16];
        #pragma unroll
        for (int off = 1; off < 16; off <<= 1) lv += __shfl_xor(lv, off, 64);
        if (slot == 0) lbuf[c] = lv;
    }
    __syncthreads();
    if (t < CQ) {
        ws[WS_ML + (size_t)blk * 32 + t]      = mbuf[t];
        ws[WS_ML + (size_t)blk * 32 + 16 + t] = lbuf[t];
    }

    // ---- Phase 3: pooling (wave owns 64 nodes, lane owns float4 of D) ----
    int wave = t >> 6, lane = t & 63;
    float4 acc[CQ];
    #pragma unroll
    for (int c = 0; c < CQ; ++c) acc[c] = make_float4(0.f, 0.f, 0.f, 0.f);

    const float4* xq = (const float4*)x + (size_t)(gn0 + wave * 64) * 64 + lane;
    for (int nq = 0; nq < 16; ++nq) {          // node quads
        float4 x0 = xq[(size_t)(nq * 4 + 0) * 64];
        float4 x1 = xq[(size_t)(nq * 4 + 1) * 64];
        float4 x2 = xq[(size_t)(nq * 4 + 2) * 64];
        float4 x3 = xq[(size_t)(nq * 4 + 3) * 64];
        #pragma unroll
        for (int c = 0; c < CQ; ++c) {
            float4 ev = *(const float4*)&wlds[c * 256 + wave * 64 + nq * 4];
            acc[c].x += ev.x * x0.x + ev.y * x1.x + ev.z * x2.x + ev.w * x3.x;
            acc[c].y += ev.x * x0.y + ev.y * x1.y + ev.z * x2.y + ev.w * x3.y;
            acc[c].z += ev.x * x0.z + ev.y * x1.z + ev.z * x2.z + ev.w * x3.z;
            acc[c].w += ev.x * x0.w + ev.y * x1.w + ev.z * x2.w + ev.w * x3.w;
        }
    }

    // cross-wave combine; qlds no longer needed -> reuse as scratch
    float* sdata = (float*)qlds;               // [16][256]
    __syncthreads();
    for (int w = 0; w < 4; ++w) {
        if (wave == w) {
            #pragma unroll
            for (int c = 0; c < CQ; ++c) {
                float* dst = &sdata[c * 256 + lane * 4];
                if (w == 0) {
                    dst[0] = acc[c].x; dst[1] = acc[c].y;
                    dst[2] = acc[c].z; dst[3] = acc[c].w;
                } else {
                    dst[0] += acc[c].x; dst[1] += acc[c].y;
                    dst[2] += acc[c].z; dst[3] += acc[c].w;
                }
            }
        }
        __syncthreads();
    }
    float* po = ws + WS_PL + (size_t)blk * (CQ * 256);
    #pragma unroll
    for (int i = 0; i < CQ; ++i) po[t + i * 256] = sdata[t + i * 256];
}

// ---------------------------------------------------------------------------
// E: combine 8 chunk partials (m,l,pooled) -> pooled row; LN; MLP -> logits.
// Also writes final (m, 1/l) per (b,c) for kAttn.  grid 1024, block 256.
__global__ __launch_bounds__(256) void kE(float* __restrict__ ws,
        const float* __restrict__ lnG12, const float* __restrict__ lnB12,
        const float* __restrict__ wA12,  const float* __restrict__ bA12,
        const float* __restrict__ wB12,  const float* __restrict__ bB12,
        const float* __restrict__ lnG4,  const float* __restrict__ lnB4,
        const float* __restrict__ wA4,   const float* __restrict__ bA4,
        const float* __restrict__ wB4,   const float* __restrict__ bB4,
        float* __restrict__ out) {
    int bc = blockIdx.x;
    int b = bc >> 4, c = bc & 15;
    int t = threadIdx.x, wave = t >> 6, lane = t & 63;

    __shared__ float scl[NCH];
    __shared__ float sinvl;
    if (t == 0) {
        float mi[NCH], li[NCH];
        float m = -1e30f;
        for (int i = 0; i < NCH; ++i) {
            mi[i] = ws[WS_ML + (size_t)(b * NCH + i) * 32 + c];
            li[i] = ws[WS_ML + (size_t)(b * NCH + i) * 32 + 16 + c];
            m = fmaxf(m, mi[i]);
        }
        float l = 0.f;
        for (int i = 0; i < NCH; ++i) {
            float s = __expf(mi[i] - m);
            scl[i] = s;
            l += s * li[i];
        }
        float il = 1.f / l;
        sinvl = il;
        ws[WS_FML + bc] = m;
        ws[WS_FIL + bc] = il;
    }
    __syncthreads();

    float v = 0.f;
    for (int i = 0; i < NCH; ++i)
        v += scl[i] * ws[WS_PL + ((size_t)(b * NCH + i) * CQ + c) * 256 + t];
    v *= sinvl;

    __shared__ float wr1[4], wr2[4];
    float s = v;
    #pragma unroll
    for (int off = 32; off; off >>= 1) s += __shfl_xor(s, off, 64);
    if (lane == 0) wr1[wave] = s;
    __syncthreads();
    float mu = (wr1[0] + wr1[1] + wr1[2] + wr1[3]) * (1.f / 256.f);
    float dv = v - mu;
    s = dv * dv;
    #pragma unroll
    for (int off = 32; off; off >>= 1) s += __shfl_xor(s, off, 64);
    if (lane == 0) wr2[wave] = s;
    __syncthreads();
    float var = (wr2[0] + wr2[1] + wr2[2] + wr2[3]) * (1.f / 256.f);

    bool is12 = (c < 12);
    const float* lg = is12 ? lnG12 : lnG4;
    const float* lb = is12 ? lnB12 : lnB4;
    const float* wA = is12 ? wA12  : wA4;
    const float* bA = is12 ? bA12  : bA4;
    const float* wB = is12 ? wB12  : wB4;
    const float* bB = is12 ? bB12  : bB4;

    __shared__ float ylds[256];
    __shared__ float hred[256];
    __shared__ float hlds[128];
    float y = dv * rsqrtf(var + 1e-5f) * lg[t] + lb[t];
    ylds[t] = y;
    __syncthreads();
    {
        int j = t & 127, half = t >> 7;
        float hh = 0.f;
        const float* wc = wA + (size_t)half * 128 * 128 + j;
        #pragma unroll 4
        for (int d = 0; d < 128; ++d) hh += ylds[half * 128 + d] * wc[(size_t)d * 128];
        hred[t] = hh;
    }
    __syncthreads();
    if (t < 128) hlds[t] = fmaxf(hred[t] + hred[t + 128] + bA[t], 0.f);
    __syncthreads();
    if (t < 64) {
        float pp = hlds[t] * wB[t] + hlds[t + 64] * wB[t + 64];
        #pragma unroll
        for (int off = 32; off; off >>= 1) pp += __shfl_xor(pp, off, 64);
        if (t == 0) {
            float logit = pp + bB[0];
            if (is12) out[b * 12 + c] = logit;
            else      out[768 + b * 4 + (c - 12)] = logit;
        }
    }
}

// ---------------------------------------------------------------------------
// Attn: attn12[b][c][n] = exp(s - m_bc) * invl_bc.  grid 768 = (b, c<12).
__global__ __launch_bounds__(256) void kAttn(const float* __restrict__ ws,
                                             float* __restrict__ out_attn) {
    int blk = blockIdx.x;
    int b = blk / 12, c = blk % 12;
    int t = threadIdx.x;
    float m  = ws[WS_FML + b * 16 + c];
    float il = ws[WS_FIL + b * 16 + c];
    const float4* sr = (const float4*)(ws + WS_S + ((size_t)b * CQ + c) * NN);
    float4* ar = (float4*)out_attn + (size_t)(b * 12 + c) * (NN / 4);
    #pragma unroll
    for (int k = 0; k < 2; ++k) {
        float4 v = sr[t + k * 256];
        float4 e;
        e.x = __expf(v.x - m) * il;
        e.y = __expf(v.y - m) * il;
        e.z = __expf(v.z - m) * il;
        e.w = __expf(v.w - m) * il;
        ar[t + k * 256] = e;
    }
}

// ---------------------------------------------------------------------------
extern "C" void kernel_launch(void* const* d_in, const int* in_sizes, int n_in,
                              void* d_out, int out_size, void* d_ws, size_t ws_size,
                              hipStream_t stream) {
    const float* x     = (const float*)d_in[0];   // [131072, 256]
    const float* gq    = (const float*)d_in[2];   // [4, 256]
    const float* w1    = (const float*)d_in[3];   // [4, 256, 512]
    const float* b1    = (const float*)d_in[4];   // [4, 512]
    const float* w2    = (const float*)d_in[5];   // [4, 512, 768]
    const float* b2    = (const float*)d_in[6];   // [4, 768]
    const float* ln12g = (const float*)d_in[7];
    const float* ln12b = (const float*)d_in[8];
    const float* w12a  = (const float*)d_in[9];   // [256, 128]
    const float* b12a  = (const float*)d_in[10];
    const float* w12b  = (const float*)d_in[11];  // [128, 1]
    const float* b12b  = (const float*)d_in[12];
    const float* ln4g  = (const float*)d_in[13];
    const float* ln4b  = (const float*)d_in[14];
    const float* w4a   = (const float*)d_in[15];
    const float* b4a   = (const float*)d_in[16];
    const float* w4b   = (const float*)d_in[17];
    const float* b4b   = (const float*)d_in[18];

    float* out = (float*)d_out;               // [768 logits12][256 logits4][1572864 attn12]
    float* ws  = (float*)d_ws;

    kA1  <<<64,       256, 0, stream>>>(gq, w1, b1, ws);
    kA2  <<<192,      256, 0, stream>>>(w2, b2, ws);
    kF   <<<BG * NCH, 256, 0, stream>>>(x, ws);
    kE   <<<1024,     256, 0, stream>>>(ws,
            ln12g, ln12b, w12a, b12a, w12b, b12b,
            ln4g,  ln4b,  w4a,  b4a,  w4b,  b4b, out);
    kAttn<<<768,      256, 0, stream>>>(ws, out + 1024);
}